// Round 3
// baseline (164.250 us; speedup 1.0000x reference)
//
#include <hip/hip_runtime.h>

// SRL embeddings, fused single kernel — R3: max occupancy (32 waves/CU).
// Shapes fixed: B=16,S=16,L=128,D=768,A=8,T=5.
// Grid = (12 chunks, 256 (b,s)) = 3072 blocks of 256 threads; LDS ~10.9 KB ->
// 8 resident blocks/CU (32 waves, occupancy cap) + 4 queued for tail slack.
// Each block: 16 float4 columns; thread = (r = l-phase 0..15, q = col 0..15).
// - Pooling: sum hidden[b,s,l<len,chunk]/len; prefix masks -> len via
//   __syncthreads_count; masked rows never loaded.
// - Arg embeddings: reference keeps only the LAST valid t per (b,s,a); each of
//   24 slots needs one token's match list (~1 row), mostly L1/L2 re-reads.

namespace {
constexpr int Bc = 16, Sc = 16, Lc = 128, Dc = 768, Ac = 8, Tc = 5;
constexpr int NF4    = Dc / 4;          // 192 float4 per row
constexpr int CHUNK  = 16;              // float4 columns per block
constexpr int NCHUNK = NF4 / CHUNK;     // 12
constexpr int BLOCK  = 256;             // 4 waves
constexpr int RP     = BLOCK / CHUNK;   // 16 l-phases
constexpr int NSLOT  = 3 * Ac;          // 24 arg slots
constexpr int OUT1   = Bc * Sc * NF4;       // sentence output, float4 units
constexpr int OUTG   = Bc * Sc * Ac * NF4;  // per-arg-type output, float4 units
}

__global__ __launch_bounds__(BLOCK) void srl_fused(
    const float4* __restrict__ hid,
    const int*    __restrict__ sids,
    const int*    __restrict__ amask,
    const int*    __restrict__ pids,
    const int*    __restrict__ a0ids,
    const int*    __restrict__ a1ids,
    float4*       __restrict__ out)
{
  const int c   = blockIdx.x;           // column chunk 0..11
  const int bs  = blockIdx.y;           // (b,s) 0..255
  const int tid = threadIdx.x;
  const int q   = tid & (CHUNK - 1);    // float4 column within chunk
  const int r   = tid >> 4;             // l-phase 0..15

  __shared__ int    sid[Lc];
  __shared__ short  slist[NSLOT][Lc];
  __shared__ int    scnt[NSLOT];
  __shared__ float4 red[BLOCK];

  // Phase A: stage sentence ids; prefix length via __syncthreads_count.
  int mval = 0;
  if (tid < Lc) {
    sid[tid] = sids[bs * Lc + tid];
    mval     = amask[bs * Lc + tid];
  }
  const int len = __syncthreads_count(mval != 0);

  const float4* __restrict__ hrow = hid + (size_t)bs * Lc * NF4 + c * CHUNK;

  // Phase B (lanes 0..23 of wave 0, overlapped with pooling on other waves):
  // count matches for all 5 tokens in one sid scan, pick LAST valid t
  // (tok!=0 && cnt>0), build its match list.
  if (tid < NSLOT) {
    const int g = tid / Ac, a = tid % Ac;
    const int* ids = (g == 0 ? pids : (g == 1 ? a0ids : a1ids)) + (bs * Ac + a) * Tc;
    int tok[Tc], cnt[Tc];
#pragma unroll
    for (int t = 0; t < Tc; ++t) { tok[t] = ids[t]; cnt[t] = 0; }
    for (int l = 0; l < Lc; ++l) {
      const int v = sid[l];   // broadcast read
#pragma unroll
      for (int t = 0; t < Tc; ++t) cnt[t] += (v == tok[t]) ? 1 : 0;
    }
    int sel = 0, n = 0;
#pragma unroll
    for (int t = Tc - 1; t >= 0; --t) {
      if (n == 0 && tok[t] != 0 && cnt[t] > 0) { sel = tok[t]; n = cnt[t]; }
    }
    scnt[tid] = n;
    if (n > 0) {
      int k = 0;
      for (int l = 0; l < Lc; ++l)
        if (sid[l] == sel) slist[tid][k++] = (short)l;
    }
  }

  // Phase C: pooling partial sums over the valid prefix, l-split by r.
  float ax = 0.f, ay = 0.f, az = 0.f, aw = 0.f;
#pragma unroll 4
  for (int l = r; l < len; l += RP) {
    const float4 v = hrow[l * NF4 + q];
    ax += v.x; ay += v.y; az += v.z; aw += v.w;
  }
  red[tid] = make_float4(ax, ay, az, aw);
  __syncthreads();   // red ready; also publishes scnt/slist for Phase D

  // Phase C2 stage 1: 64 threads fold 16 phases -> 4 (each thread sums its
  // own 4 disjoint phase slots; no cross-thread hazard before the sync).
  if (tid < 64) {
    const int qq = tid & (CHUNK - 1);
    const int g  = tid >> 4;            // 0..3 -> phases 4g..4g+3
    float4 s = red[(4 * g) * CHUNK + qq];
#pragma unroll
    for (int p = 1; p < 4; ++p) {
      const float4 t = red[(4 * g + p) * CHUNK + qq];
      s.x += t.x; s.y += t.y; s.z += t.z; s.w += t.w;
    }
    red[g * CHUNK + qq] = s;
  }
  __syncthreads();

  // Phase C2 stage 2: 16 threads fold 4 -> 1, scale, write.
  if (tid < CHUNK) {
    float4 s = red[tid];
#pragma unroll
    for (int g = 1; g < 4; ++g) {
      const float4 t = red[g * CHUNK + tid];
      s.x += t.x; s.y += t.y; s.z += t.z; s.w += t.w;
    }
    const float inv = 1.0f / (float)(len > 0 ? len : 1);
    s.x *= inv; s.y *= inv; s.z *= inv; s.w *= inv;
    out[bs * NF4 + c * CHUNK + tid] = s;
  }

  // Phase D: arg embeddings. Slots strided over the 16 l-phases; match rows
  // mostly hit L1/L2 (same columns streamed in Phase C).
  for (int j = r; j < NSLOT; j += RP) {
    const int n = scnt[j];
    float ox = 0.f, oy = 0.f, oz = 0.f, ow = 0.f;
    if (n > 0) {
      for (int i = 0; i < n; ++i) {
        const int l = (int)slist[j][i];   // broadcast read
        const float4 v = hrow[l * NF4 + q];
        ox += v.x; oy += v.y; oz += v.z; ow += v.w;
      }
      const float inv = 1.0f / (float)n;
      ox *= inv; oy *= inv; oz *= inv; ow *= inv;
    }
    const int g = j / Ac, a = j % Ac;
    out[OUT1 + g * OUTG + (bs * Ac + a) * NF4 + c * CHUNK + q] =
        make_float4(ox, oy, oz, ow);
  }
}

extern "C" void kernel_launch(void* const* d_in, const int* in_sizes, int n_in,
                              void* d_out, int out_size, void* d_ws, size_t ws_size,
                              hipStream_t stream) {
  const float4* hid   = (const float4*)d_in[0];
  const int*    sids  = (const int*)d_in[1];
  const int*    amask = (const int*)d_in[2];
  const int*    pids  = (const int*)d_in[3];
  const int*    a0ids = (const int*)d_in[4];
  const int*    a1ids = (const int*)d_in[5];
  float4*       out   = (float4*)d_out;

  srl_fused<<<dim3(NCHUNK, Bc * Sc), dim3(BLOCK), 0, stream>>>(
      hid, sids, amask, pids, a0ids, a1ids, out);
}

// Round 4
// 159.739 us; speedup vs baseline: 1.0282x; 1.0282x over previous
//
#include <hip/hip_runtime.h>

// SRL embeddings, fused single kernel — R4: R2 geometry (best measured) +
// bitmask Phase B (single sid scan, no slist rebuild, LDS 17 KB -> ~5 KB).
// Shapes fixed: B=16,S=16,L=128,D=768,A=8,T=5.
// Grid = (6 chunks, 256 (b,s)) = 1536 blocks of 256 threads (6 blocks/CU,
// 24 waves/CU). Each block: 32 float4 columns; thread = (r=l-phase 0..7,
// q=col 0..31).
// - Pooling: sum hidden[b,s,l<len,chunk]/len; prefix masks -> len via
//   __syncthreads_count; masked rows never loaded.
// - Arg embeddings: reference keeps only the LAST valid t per (b,s,a); each
//   of 24 slots gets a 128-bit row-match bitmask (built in the count scan),
//   Phase D walks set bits (~1.1 rows), re-reading columns from L1/L2.

namespace {
constexpr int Bc = 16, Sc = 16, Lc = 128, Dc = 768, Ac = 8, Tc = 5;
constexpr int NF4    = Dc / 4;          // 192 float4 per row
constexpr int CHUNK  = 32;              // float4 columns per block
constexpr int NCHUNK = NF4 / CHUNK;     // 6
constexpr int BLOCK  = 256;             // 4 waves
constexpr int RP     = BLOCK / CHUNK;   // 8 l-phases
constexpr int NSLOT  = 3 * Ac;          // 24 arg slots
constexpr int OUT1   = Bc * Sc * NF4;       // sentence output, float4 units
constexpr int OUTG   = Bc * Sc * Ac * NF4;  // per-arg-type output, float4 units
}

__global__ __launch_bounds__(BLOCK) void srl_fused(
    const float4* __restrict__ hid,
    const int*    __restrict__ sids,
    const int*    __restrict__ amask,
    const int*    __restrict__ pids,
    const int*    __restrict__ a0ids,
    const int*    __restrict__ a1ids,
    float4*       __restrict__ out)
{
  const int c   = blockIdx.x;           // column chunk 0..5
  const int bs  = blockIdx.y;           // (b,s) 0..255
  const int tid = threadIdx.x;
  const int q   = tid & (CHUNK - 1);    // float4 column within chunk
  const int r   = tid >> 5;             // l-phase 0..7

  __shared__ int                sid[Lc];
  __shared__ unsigned long long smask[NSLOT][2];  // 128-bit row-match mask
  __shared__ int                scnt[NSLOT];
  __shared__ float4             red[BLOCK];

  // Phase A: stage sentence ids; prefix length via __syncthreads_count.
  int mval = 0;
  if (tid < Lc) {
    sid[tid] = sids[bs * Lc + tid];
    mval     = amask[bs * Lc + tid];
  }
  const int len = __syncthreads_count(mval != 0);

  const float4* __restrict__ hrow = hid + (size_t)bs * Lc * NF4 + c * CHUNK;

  // Phase B (lanes 0..23 of wave 0, overlapped with pooling on other waves):
  // one sid scan building a 128-bit match bitmask per arg token; pick the
  // LAST valid t (tok!=0 && popcount>0); publish its mask + count.
  if (tid < NSLOT) {
    const int g = tid / Ac, a = tid % Ac;
    const int* ids = (g == 0 ? pids : (g == 1 ? a0ids : a1ids)) + (bs * Ac + a) * Tc;
    int tok[Tc];
    unsigned long long m0[Tc], m1[Tc];
#pragma unroll
    for (int t = 0; t < Tc; ++t) { tok[t] = ids[t]; m0[t] = 0ull; m1[t] = 0ull; }
#pragma unroll 2
    for (int l = 0; l < 64; ++l) {
      const int v = sid[l];             // broadcast read
      const unsigned long long bit = 1ull << l;
#pragma unroll
      for (int t = 0; t < Tc; ++t) if (v == tok[t]) m0[t] |= bit;
    }
#pragma unroll 2
    for (int l = 0; l < 64; ++l) {
      const int v = sid[64 + l];        // broadcast read
      const unsigned long long bit = 1ull << l;
#pragma unroll
      for (int t = 0; t < Tc; ++t) if (v == tok[t]) m1[t] |= bit;
    }
    unsigned long long s0 = 0ull, s1 = 0ull;
    int n = 0;
#pragma unroll
    for (int t = Tc - 1; t >= 0; --t) {
      const int cnt = __popcll(m0[t]) + __popcll(m1[t]);
      if (n == 0 && tok[t] != 0 && cnt > 0) { n = cnt; s0 = m0[t]; s1 = m1[t]; }
    }
    scnt[tid]     = n;
    smask[tid][0] = s0;
    smask[tid][1] = s1;
  }

  // Phase C: pooling partial sums over the valid prefix, l-split by r.
  float ax = 0.f, ay = 0.f, az = 0.f, aw = 0.f;
#pragma unroll 4
  for (int l = r; l < len; l += RP) {
    const float4 v = hrow[l * NF4 + q];
    ax += v.x; ay += v.y; az += v.z; aw += v.w;
  }
  red[tid] = make_float4(ax, ay, az, aw);
  __syncthreads();   // red ready; also publishes scnt/smask for Phase D

  // Phase C2: reduce the 8 l-phases, divide by len, write sentence embedding.
  if (tid < CHUNK) {
    float4 s = red[tid];
#pragma unroll
    for (int p = 1; p < RP; ++p) {
      const float4 t = red[p * CHUNK + tid];
      s.x += t.x; s.y += t.y; s.z += t.z; s.w += t.w;
    }
    const float inv = 1.0f / (float)(len > 0 ? len : 1);
    s.x *= inv; s.y *= inv; s.z *= inv; s.w *= inv;
    out[bs * NF4 + c * CHUNK + tid] = s;
  }

  // Phase D: arg embeddings. 3 slots per l-phase; walk set bits of the
  // selected token's bitmask; match rows hit L1/L2 (streamed in Phase C).
  for (int j = r; j < NSLOT; j += RP) {
    const int n = scnt[j];
    float ox = 0.f, oy = 0.f, oz = 0.f, ow = 0.f;
    if (n > 0) {
#pragma unroll
      for (int w = 0; w < 2; ++w) {
        unsigned long long m = smask[j][w];   // broadcast read
        const int base = w * 64;
        while (m) {
          const int l = base + (int)__builtin_ctzll(m);
          m &= m - 1;
          const float4 v = hrow[l * NF4 + q];
          ox += v.x; oy += v.y; oz += v.z; ow += v.w;
        }
      }
      const float inv = 1.0f / (float)n;
      ox *= inv; oy *= inv; oz *= inv; ow *= inv;
    }
    const int g = j / Ac, a = j % Ac;
    out[OUT1 + g * OUTG + (bs * Ac + a) * NF4 + c * CHUNK + q] =
        make_float4(ox, oy, oz, ow);
  }
}

extern "C" void kernel_launch(void* const* d_in, const int* in_sizes, int n_in,
                              void* d_out, int out_size, void* d_ws, size_t ws_size,
                              hipStream_t stream) {
  const float4* hid   = (const float4*)d_in[0];
  const int*    sids  = (const int*)d_in[1];
  const int*    amask = (const int*)d_in[2];
  const int*    pids  = (const int*)d_in[3];
  const int*    a0ids = (const int*)d_in[4];
  const int*    a1ids = (const int*)d_in[5];
  float4*       out   = (float4*)d_out;

  srl_fused<<<dim3(NCHUNK, Bc * Sc), dim3(BLOCK), 0, stream>>>(
      hid, sids, amask, pids, a0ids, a1ids, out);
}